// Round 7
// baseline (164.738 us; speedup 1.0000x reference)
//
#include <hip/hip_runtime.h>
#include <hip/hip_bf16.h>
#include <math.h>

typedef unsigned short u16;
typedef unsigned char u8;
typedef unsigned int u32;
typedef long long i64;
typedef __attribute__((ext_vector_type(4))) float f32x4;
typedef __attribute__((ext_vector_type(4))) int   i32x4;

// -------------------------------------------------- fp32 -> int8 (x127 symmetric)
// l2-normed inputs: |x| <= 1 -> rint(x*127) in [-127,127]. EXACT i32 MFMA
// accumulation; dequant (1/(127^2*temp)) folded into gemm epilogue.
// PLAIN ROW-MAJOR output (i8 16x16x64 lane operands are naturally contiguous).
__global__ void cvt_fused(const float* __restrict__ F, const float* __restrict__ T,
                          u32* __restrict__ Fb, u32* __restrict__ Tb,
                          float* __restrict__ out) {
    const int idx = blockIdx.x * blockDim.x + threadIdx.x;
    if (idx == 0) out[0] = 0.f;
    const float* s;
    u32* d;
    int i;
    if (idx < 65536) { s = F; d = Fb; i = idx; }
    else             { s = T; d = Tb; i = idx - 65536; }
    const float4 v0 = *(const float4*)(s + (size_t)i * 8);
    const float4 v1 = *(const float4*)(s + (size_t)i * 8 + 4);
    const int q0 = __float2int_rn(v0.x * 127.f), q1 = __float2int_rn(v0.y * 127.f);
    const int q2 = __float2int_rn(v0.z * 127.f), q3 = __float2int_rn(v0.w * 127.f);
    const int q4 = __float2int_rn(v1.x * 127.f), q5 = __float2int_rn(v1.y * 127.f);
    const int q6 = __float2int_rn(v1.z * 127.f), q7 = __float2int_rn(v1.w * 127.f);
    uint2 o;
    o.x = (u32)(q0 & 255) | ((u32)(q1 & 255) << 8) | ((u32)(q2 & 255) << 16) | ((u32)(q3 & 255) << 24);
    o.y = (u32)(q4 & 255) | ((u32)(q5 & 255) << 8) | ((u32)(q6 & 255) << 16) | ((u32)(q7 & 255) << 24);
    ((uint2*)d)[i] = o;
}

// ---------------------------------------------------------------- GEMM + max
#define GLB_AS __attribute__((address_space(1)))
#define LDS_AS __attribute__((address_space(3)))

__device__ __forceinline__ void gload_lds16(const void* g, void* l) {
    __builtin_amdgcn_global_load_lds((const GLB_AS void*)g, (LDS_AS void*)l, 16, 0, 0);
}

// A: F i8 [1024 x 512], B: T i8 [32768 x 512] (row-major).
// sim[i*1024+j] = max_{q<32} dot(A[i],B[j*32+q]) / (127^2*temp)
//
// R17: A DIRECT FROM GLOBAL (in-loop, short-lived), B in LDS.
// R16 post-mortem: gemm ~31us is LDS-pipe-dominated (2 MB ds_read/CU ~ 12us
// > MFMA 8.7us); R15 proved scheduling can't overlap them better. So shrink
// LDS: A's tile (64 KB) is shared by all 8 resident blocks of a dispatch
// generation (same bm) -> A-direct is L1-resident. i8 lane fragment is a
// contiguous 16B at row*512 + k0 + h*64 + fq*16: one dwordx4 with immediate
// offset from 4 per-lane base pointers (k-loop unrolled). LDS reads halve
// (12 -> ~6us), staging halves (4 glds/step), lA deleted (LDS 32->16 KB).
// UNLIKE R14 (spilled): aF is loaded INSIDE the h-loop, consumed at once
// (16 regs, never live across a barrier); addressing is 8 regs.
// Budget: acc 64 + bF 16 + aF 16 + addr ~25 ~= 121 < 128 cap @ 4 blk/CU.
// Data path byte-identical to R16 -> bit-exact.
//
// LDS (B): row-major 128-B rows; 16B chunk c of row r at slot c^(r&7)
// (R4/R9-verified). Lane (frow,fq), h reads chunk 4h+fq -> slot (4h+fq)^r7:
// per quarter-wave 8 slots x 2 rows = benign 2-way (free, m136).
__global__ __launch_bounds__(256, 4)
void gemm_max(const u8* __restrict__ A, const u8* __restrict__ B,
              const float* __restrict__ temp_ptr, float* __restrict__ sim) {
    __shared__ __align__(16) u8 lB[128 * 128];   // 16 KB
    const int bid = blockIdx.x;                  // 0..2047
    const int bn  = ((bid & 7) << 5) | ((bid >> 3) & 31);  // XCD slab: xcd*32 + local
    const int bm  = bid >> 8;                               // 0..7, inner sweep
    const int tid  = threadIdx.x;
    const int wave = tid >> 6;
    const int lane = tid & 63;
    const int wm = wave >> 1;       // 0..1: rows wm*64
    const int wn = wave & 1;        // 0..1: cols wn*64

    i32x4 acc[4][4] = {};           // 64 VGPRs, exact i32

    // B staging: one glds = 8 rows x 128B. lane -> srow = lane>>3, slot chunk
    // l&7 holds global chunk (l&7)^srow.
    const int srow = lane >> 3;
    const int aoff = srow * 512 + (((lane & 7) ^ srow) << 4);   // per-lane global offset
    const u8* gB = B + (size_t)(bn * 128) * 512 + aoff;         // + grp*4096 + k0

    const int frow = lane & 15;
    const int fq   = lane >> 4;
    const int r7   = frow & 7;

    // A-direct per-lane base pointers (one per mt); k0 + h*64 folds into the
    // load's immediate offset after full unroll.
    const u8* gAm[4];
#pragma unroll
    for (int mt = 0; mt < 4; ++mt)
        gAm[mt] = A + (size_t)(bm * 128 + wm * 64 + mt * 16 + frow) * 512 + (fq << 4);

#pragma unroll
    for (int kk = 0; kk < 4; ++kk) {
        const int k0 = kk * 128;
        // B: 16 groups of 8 rows; this wave stages groups wave+4g.
#pragma unroll
        for (int g = 0; g < 4; ++g)
            gload_lds16(gB + (wave + 4 * g) * 4096 + k0, lB + (wave + 4 * g) * 1024);
        __syncthreads();

#pragma unroll
        for (int h = 0; h < 2; ++h) {           // K=64 halves of the 128-block
            const int coff = (((h << 2) + fq) ^ r7) << 4;
            i32x4 aF[4], bF[4];
#pragma unroll
            for (int mt = 0; mt < 4; ++mt)
                aF[mt] = *(const i32x4*)(gAm[mt] + k0 + h * 64);   // L1/L2 direct
#pragma unroll
            for (int nt = 0; nt < 4; ++nt)
                bF[nt] = *(const i32x4*)&lB[(wn * 64 + nt * 16 + frow) * 128 + coff];
#pragma unroll
            for (int mt = 0; mt < 4; ++mt)
#pragma unroll
                for (int nt = 0; nt < 4; ++nt)
                    acc[mt][nt] = __builtin_amdgcn_mfma_i32_16x16x64_i8(
                        aF[mt], bF[nt], acc[mt][nt], 0, 0, 0);
        }
        __syncthreads();
    }

    // epilogue: C row = bm*128 + wm*64 + mt*16 + fq*4 + rr ;
    //           col   = bn*128 + wn*64 + nt*16 + (l&15);  j = col>>5
    const float inv = 1.0f / (16129.0f * (*temp_ptr));
    const int jb = (bn * 128 + wn * 64) >> 5;
#pragma unroll
    for (int mt = 0; mt < 4; ++mt) {
#pragma unroll
        for (int rr = 0; rr < 4; ++rr) {
            int m0 = max(acc[mt][0][rr], acc[mt][1][rr]);
            int m1 = max(acc[mt][2][rr], acc[mt][3][rr]);
#pragma unroll
            for (int off = 1; off < 16; off <<= 1) {
                m0 = max(m0, __shfl_xor(m0, off));
                m1 = max(m1, __shfl_xor(m1, off));
            }
            if ((lane & 15) == 0) {
                const int row = bm * 128 + wm * 64 + mt * 16 + fq * 4 + rr;
                sim[row * 1024 + jb]     = (float)m0 * inv;
                sim[row * 1024 + jb + 1] = (float)m1 * inv;
            }
        }
    }
}

// ---------------------------------------------------------------- per-row loss
// ONE WAVE PER ROW, zero LDS, zero barriers. Row (1024 fp32) in 16 regs/lane.
__device__ __forceinline__ u32 f2key(float x) {
    u32 b = __float_as_uint(x);
    return (b & 0x80000000u) ? ~b : (b | 0x80000000u);
}
__device__ __forceinline__ float key2f(u32 k) {
    return __uint_as_float((k & 0x80000000u) ? (k & 0x7fffffffu) : ~k);
}

__global__ __launch_bounds__(256)
void row_loss(const float* __restrict__ sim, float* __restrict__ out) {
    const int tid = threadIdx.x;
    const int lane = tid & 63;
    const int wv = tid >> 6;
    const int i = blockIdx.x * 4 + wv;          // row index

    float v[16];
    const float4* rp = (const float4*)(sim + (size_t)i * 1024);
#pragma unroll
    for (int t = 0; t < 4; ++t) {
        float4 f = rp[t * 64 + lane];
        v[t * 4 + 0] = f.x; v[t * 4 + 1] = f.y; v[t * 4 + 2] = f.z; v[t * 4 + 3] = f.w;
    }

    const int dslot = ((i >> 8) << 2) | (i & 3);
    const int dlane = (i >> 2) & 63;

    u32 k[16];
#pragma unroll
    for (int t = 0; t < 16; ++t) {
        u32 kk = f2key(v[t]);
        k[t] = (lane == dlane && t == dslot) ? 0u : kk;   // diag -> below any finite key
    }

    float pv = 0.f;
#pragma unroll
    for (int t = 0; t < 16; ++t) if (t == dslot) pv = v[t];
    const float pos = __shfl(pv, dlane);

    float m = v[0];
#pragma unroll
    for (int t = 1; t < 16; ++t) m = fmaxf(m, v[t]);
#pragma unroll
    for (int off = 32; off > 0; off >>= 1) m = fmaxf(m, __shfl_xor(m, off));
    float s = 0.f;
#pragma unroll
    for (int t = 0; t < 16; ++t) s += __expf(v[t] - m);
#pragma unroll
    for (int off = 32; off > 0; off >>= 1) s += __shfl_xor(s, off);
    const float loss_std = m + __logf(s) - pos;

    // binary search: largest x with count(key >= x) >= 512
    u32 lo = 0u, hi = 0xFFFFFFFFu;
    while (lo < hi) {
        const u32 span = hi - lo;
        const u32 mid = lo + (span >> 1) + (span & 1u);
        int cnt = 0;
#pragma unroll
        for (int t = 0; t < 16; ++t) cnt += (k[t] >= mid);
#pragma unroll
        for (int off = 32; off > 0; off >>= 1) cnt += __shfl_xor(cnt, off);
        if (cnt >= 512) lo = mid; else hi = mid - 1;
    }
    const u32 t_key = lo;
    const float tval = key2f(t_key);

    float se = 0.f;
    int cgt = 0;
#pragma unroll
    for (int t = 0; t < 16; ++t) {
        if (k[t] > t_key) { se += __expf(v[t] - m); ++cgt; }
    }
#pragma unroll
    for (int off = 32; off > 0; off >>= 1) se += __shfl_xor(se, off);
#pragma unroll
    for (int off = 32; off > 0; off >>= 1) cgt += __shfl_xor(cgt, off);

    const float sh = se + (float)(512 - cgt) * __expf(tval - m) + __expf(pos - m);
    const float hard = m + __logf(sh) - pos;

    if (lane == 0)
        atomicAdd(out, (loss_std + 0.5f * hard) * (1.0f / 1024.0f));
}

// ---------------------------------------------------------------- launch
extern "C" void kernel_launch(void* const* d_in, const int* in_sizes, int n_in,
                              void* d_out, int out_size, void* d_ws, size_t ws_size,
                              hipStream_t stream) {
    const float* F    = (const float*)d_in[0];   // 1024*512
    const float* T    = (const float*)d_in[1];   // 1024*32*512
    const float* temp = (const float*)d_in[2];   // scalar
    float* out = (float*)d_out;

    char* ws = (char*)d_ws;
    u32*  Fb8 = (u32*)ws;                                   // 0.5 MB i8
    u32*  Tb8 = (u32*)(ws + (1u << 20));                    // 16 MB i8
    float* sim = (float*)(ws + (1u << 20) + (32u << 20));   // 4 MB

    cvt_fused<<<8448, 256, 0, stream>>>(F, T, Fb8, Tb8, out);

    gemm_max<<<2048, 256, 0, stream>>>((const u8*)Fb8, (const u8*)Tb8, temp, sim);

    row_loss<<<256, 256, 0, stream>>>(sim, out);
}

// Round 8
// 149.642 us; speedup vs baseline: 1.1009x; 1.1009x over previous
//
#include <hip/hip_runtime.h>
#include <hip/hip_bf16.h>
#include <math.h>

typedef unsigned short u16;
typedef unsigned char u8;
typedef unsigned int u32;
typedef long long i64;
typedef __attribute__((ext_vector_type(4))) float f32x4;
typedef __attribute__((ext_vector_type(4))) int   i32x4;

// -------------------------------------------------- fp32 -> int8 (x127 symmetric)
// l2-normed inputs: |x| <= 1 -> rint(x*127) in [-127,127]. EXACT i32 MFMA
// accumulation; dequant (1/(127^2*temp)) folded into gemm epilogue.
// Quant noise sigma_dot ~0.0032 (vs fp8's 0.0022); both loss terms are
// per-row shift-invariant so selection bias cancels.
//
// PLAIN ROW-MAJOR output: the i8 16x16x64 MFMA lane operand (k=16g+c) is a
// naturally contiguous 16B chunk of a row-major K-block.
__global__ void cvt_fused(const float* __restrict__ F, const float* __restrict__ T,
                          u32* __restrict__ Fb, u32* __restrict__ Tb,
                          float* __restrict__ out) {
    const int idx = blockIdx.x * blockDim.x + threadIdx.x;
    if (idx == 0) out[0] = 0.f;
    const float* s;
    u32* d;
    int i;
    if (idx < 65536) { s = F; d = Fb; i = idx; }
    else             { s = T; d = Tb; i = idx - 65536; }
    const float4 v0 = *(const float4*)(s + (size_t)i * 8);
    const float4 v1 = *(const float4*)(s + (size_t)i * 8 + 4);
    const int q0 = __float2int_rn(v0.x * 127.f), q1 = __float2int_rn(v0.y * 127.f);
    const int q2 = __float2int_rn(v0.z * 127.f), q3 = __float2int_rn(v0.w * 127.f);
    const int q4 = __float2int_rn(v1.x * 127.f), q5 = __float2int_rn(v1.y * 127.f);
    const int q6 = __float2int_rn(v1.z * 127.f), q7 = __float2int_rn(v1.w * 127.f);
    uint2 o;
    o.x = (u32)(q0 & 255) | ((u32)(q1 & 255) << 8) | ((u32)(q2 & 255) << 16) | ((u32)(q3 & 255) << 24);
    o.y = (u32)(q4 & 255) | ((u32)(q5 & 255) << 8) | ((u32)(q6 & 255) << 16) | ((u32)(q7 & 255) << 24);
    ((uint2*)d)[i] = o;
}

// ---------------------------------------------------------------- GEMM + max
#define GLB_AS __attribute__((address_space(1)))
#define LDS_AS __attribute__((address_space(3)))

__device__ __forceinline__ void gload_lds16(const void* g, void* l) {
    __builtin_amdgcn_global_load_lds((const GLB_AS void*)g, (LDS_AS void*)l, 16, 0, 0);
}

// A: F i8 [1024 x 512], B: T i8 [32768 x 512] (row-major).
// sim[i*1024+j] = max_{q<32} dot(A[i],B[j*32+q]) / (127^2*temp)
//
// R18 = R16 verbatim (best known: 150.6 us total, gemm ~31 us).
// Session ledger: pipe-shrinks won (R12 64x64 wave tile +9us; R16 i8 K=64
// MFMA +4us). ALL scheduling attacks on this 4-K-step loop lost or were
// neutral (R11 dbuf -4, R13 counted-vmcnt -9, R15 dbuf@full-occ 0), and both
// LDS-bypass attempts lost (R14 spill -31, R17 latency-on-MFMA-chain -13).
// Structural floor analysis: MFMA 7.8us + LDS ~12us are BALANCED at this
// tile (0.031 B/MAC vs 0.036 pipe ratio) -> overlap tuning has no headroom;
// the ~11us barrier/latency residual resisted 5 independent attacks on a
// K-loop too short (4 iters) to amortize a deep pipeline. LDS staging is
// kept NOT for bandwidth but for latency decoupling (R17's lesson).
//
// LDS: row-major 128-B rows; 16B chunk c of row r at slot c^(r&7)
// (R4/R9-verified). Lane (frow,fq), h reads chunk 4h+fq -> slot (4h+fq)^r7:
// per quarter-wave 8 slots x 2 rows = benign 2-way (free, m136).
__global__ __launch_bounds__(256, 4)
void gemm_max(const u8* __restrict__ A, const u8* __restrict__ B,
              const float* __restrict__ temp_ptr, float* __restrict__ sim) {
    __shared__ __align__(16) u8 lA[128 * 128];   // 16 KB
    __shared__ __align__(16) u8 lB[128 * 128];   // 16 KB
    const int bid = blockIdx.x;                  // 0..2047
    const int bn  = ((bid & 7) << 5) | ((bid >> 3) & 31);  // XCD slab: xcd*32 + local
    const int bm  = bid >> 8;                               // 0..7, inner sweep
    const int tid  = threadIdx.x;
    const int wave = tid >> 6;
    const int lane = tid & 63;
    const int wm = wave >> 1;       // 0..1: rows wm*64
    const int wn = wave & 1;        // 0..1: cols wn*64

    i32x4 acc[4][4] = {};           // 64 VGPRs, exact i32

    // staging: one glds = 8 rows x 128B. lane -> srow = lane>>3, slot chunk
    // l&7 holds global chunk (l&7)^srow.
    const int srow = lane >> 3;
    const int aoff = srow * 512 + (((lane & 7) ^ srow) << 4);   // per-lane global offset
    const u8* gA = A + (size_t)(bm * 128) * 512 + aoff;         // + grp*4096 + k0
    const u8* gB = B + (size_t)(bn * 128) * 512 + aoff;         // + grp*4096 + k0

    const int frow = lane & 15;
    const int fq   = lane >> 4;
    const int r7   = frow & 7;

    for (int k0 = 0; k0 < 512; k0 += 128) {
        // A and B each: 16 groups of 8 rows; this wave stages groups wave+4g.
#pragma unroll
        for (int g = 0; g < 4; ++g)
            gload_lds16(gA + (wave + 4 * g) * 4096 + k0, lA + (wave + 4 * g) * 1024);
#pragma unroll
        for (int g = 0; g < 4; ++g)
            gload_lds16(gB + (wave + 4 * g) * 4096 + k0, lB + (wave + 4 * g) * 1024);
        __syncthreads();

#pragma unroll
        for (int h = 0; h < 2; ++h) {           // K=64 halves of the 128-block
            const int coff = (((h << 2) + fq) ^ r7) << 4;
            i32x4 aF[4], bF[4];
#pragma unroll
            for (int mt = 0; mt < 4; ++mt)
                aF[mt] = *(const i32x4*)&lA[(wm * 64 + mt * 16 + frow) * 128 + coff];
#pragma unroll
            for (int nt = 0; nt < 4; ++nt)
                bF[nt] = *(const i32x4*)&lB[(wn * 64 + nt * 16 + frow) * 128 + coff];
#pragma unroll
            for (int mt = 0; mt < 4; ++mt)
#pragma unroll
                for (int nt = 0; nt < 4; ++nt)
                    acc[mt][nt] = __builtin_amdgcn_mfma_i32_16x16x64_i8(
                        aF[mt], bF[nt], acc[mt][nt], 0, 0, 0);
        }
        __syncthreads();
    }

    // epilogue: C row = bm*128 + wm*64 + mt*16 + fq*4 + rr ;
    //           col   = bn*128 + wn*64 + nt*16 + (l&15);  j = col>>5
    // int max is exact; convert once, then dequant.
    const float inv = 1.0f / (16129.0f * (*temp_ptr));
    const int jb = (bn * 128 + wn * 64) >> 5;
#pragma unroll
    for (int mt = 0; mt < 4; ++mt) {
#pragma unroll
        for (int rr = 0; rr < 4; ++rr) {
            int m0 = max(acc[mt][0][rr], acc[mt][1][rr]);
            int m1 = max(acc[mt][2][rr], acc[mt][3][rr]);
#pragma unroll
            for (int off = 1; off < 16; off <<= 1) {
                m0 = max(m0, __shfl_xor(m0, off));
                m1 = max(m1, __shfl_xor(m1, off));
            }
            if ((lane & 15) == 0) {
                const int row = bm * 128 + wm * 64 + mt * 16 + fq * 4 + rr;
                sim[row * 1024 + jb]     = (float)m0 * inv;
                sim[row * 1024 + jb + 1] = (float)m1 * inv;
            }
        }
    }
}

// ---------------------------------------------------------------- per-row loss
// ONE WAVE PER ROW, zero LDS, zero barriers. Row (1024 fp32) in 16 regs/lane.
__device__ __forceinline__ u32 f2key(float x) {
    u32 b = __float_as_uint(x);
    return (b & 0x80000000u) ? ~b : (b | 0x80000000u);
}
__device__ __forceinline__ float key2f(u32 k) {
    return __uint_as_float((k & 0x80000000u) ? (k & 0x7fffffffu) : ~k);
}

__global__ __launch_bounds__(256)
void row_loss(const float* __restrict__ sim, float* __restrict__ out) {
    const int tid = threadIdx.x;
    const int lane = tid & 63;
    const int wv = tid >> 6;
    const int i = blockIdx.x * 4 + wv;          // row index

    float v[16];
    const float4* rp = (const float4*)(sim + (size_t)i * 1024);
#pragma unroll
    for (int t = 0; t < 4; ++t) {
        float4 f = rp[t * 64 + lane];
        v[t * 4 + 0] = f.x; v[t * 4 + 1] = f.y; v[t * 4 + 2] = f.z; v[t * 4 + 3] = f.w;
    }

    const int dslot = ((i >> 8) << 2) | (i & 3);
    const int dlane = (i >> 2) & 63;

    u32 k[16];
#pragma unroll
    for (int t = 0; t < 16; ++t) {
        u32 kk = f2key(v[t]);
        k[t] = (lane == dlane && t == dslot) ? 0u : kk;   // diag -> below any finite key
    }

    float pv = 0.f;
#pragma unroll
    for (int t = 0; t < 16; ++t) if (t == dslot) pv = v[t];
    const float pos = __shfl(pv, dlane);

    float m = v[0];
#pragma unroll
    for (int t = 1; t < 16; ++t) m = fmaxf(m, v[t]);
#pragma unroll
    for (int off = 32; off > 0; off >>= 1) m = fmaxf(m, __shfl_xor(m, off));
    float s = 0.f;
#pragma unroll
    for (int t = 0; t < 16; ++t) s += __expf(v[t] - m);
#pragma unroll
    for (int off = 32; off > 0; off >>= 1) s += __shfl_xor(s, off);
    const float loss_std = m + __logf(s) - pos;

    // binary search: largest x with count(key >= x) >= 512
    u32 lo = 0u, hi = 0xFFFFFFFFu;
    while (lo < hi) {
        const u32 span = hi - lo;
        const u32 mid = lo + (span >> 1) + (span & 1u);
        int cnt = 0;
#pragma unroll
        for (int t = 0; t < 16; ++t) cnt += (k[t] >= mid);
#pragma unroll
        for (int off = 32; off > 0; off >>= 1) cnt += __shfl_xor(cnt, off);
        if (cnt >= 512) lo = mid; else hi = mid - 1;
    }
    const u32 t_key = lo;
    const float tval = key2f(t_key);

    float se = 0.f;
    int cgt = 0;
#pragma unroll
    for (int t = 0; t < 16; ++t) {
        if (k[t] > t_key) { se += __expf(v[t] - m); ++cgt; }
    }
#pragma unroll
    for (int off = 32; off > 0; off >>= 1) se += __shfl_xor(se, off);
#pragma unroll
    for (int off = 32; off > 0; off >>= 1) cgt += __shfl_xor(cgt, off);

    const float sh = se + (float)(512 - cgt) * __expf(tval - m) + __expf(pos - m);
    const float hard = m + __logf(sh) - pos;

    if (lane == 0)
        atomicAdd(out, (loss_std + 0.5f * hard) * (1.0f / 1024.0f));
}

// ---------------------------------------------------------------- launch
extern "C" void kernel_launch(void* const* d_in, const int* in_sizes, int n_in,
                              void* d_out, int out_size, void* d_ws, size_t ws_size,
                              hipStream_t stream) {
    const float* F    = (const float*)d_in[0];   // 1024*512
    const float* T    = (const float*)d_in[1];   // 1024*32*512
    const float* temp = (const float*)d_in[2];   // scalar
    float* out = (float*)d_out;

    char* ws = (char*)d_ws;
    u32*  Fb8 = (u32*)ws;                                   // 0.5 MB i8
    u32*  Tb8 = (u32*)(ws + (1u << 20));                    // 16 MB i8
    float* sim = (float*)(ws + (1u << 20) + (32u << 20));   // 4 MB

    cvt_fused<<<8448, 256, 0, stream>>>(F, T, Fb8, Tb8, out);

    gemm_max<<<2048, 256, 0, stream>>>((const u8*)Fb8, (const u8*)Tb8, temp, sim);

    row_loss<<<256, 256, 0, stream>>>(sim, out);
}